// Round 10
// baseline (790.424 us; speedup 1.0000x reference)
//
#include <hip/hip_runtime.h>
#include <utility>
#include <type_traits>

// ============================================================================
// Equivariant MPNN forward (B=32, N=32, F=32, 9 comps, 2 parities, 3 iters)
// R10: ONE persistent kernel. 1024 blocks x 256 thr, exactly 4 blocks/CU
// (co-resident by construction: <=128 VGPR via __launch_bounds__(256,4),
// 23.9KB LDS); device-scope spin barrier between iterations. Edge geometry
// computed ONCE into LDS (stride 19, conflict-free); XEF lives entirely in
// LDS; own-X row kept in LDS; per-graph reduction fused at the end.
// Sizes hardcoded: Nn=32, Eb=992, B=32, F=32, NBLK=1024.
// ============================================================================

// ---------------- compile-time CG table (exact port of _build_cg) ----------
namespace cgb {
constexpr double SQ2 = 1.4142135623730951;
constexpr double cabs_(double x){ return x < 0 ? -x : x; }
constexpr double fact(int n){ double r = 1.0; for (int i = 2; i <= n; ++i) r *= (double)i; return r; }
constexpr double csqrt(double x){
  if (x <= 0.0) return 0.0;
  double g = x > 1.0 ? x : 1.0;
  for (int i = 0; i < 48; ++i) g = 0.5 * (g + x / g);
  return g;
}
constexpr double cgc(int j1,int m1,int j2,int m2,int J,int M){
  if (m1 + m2 != M) return 0.0;
  int ad = j1 - j2; if (ad < 0) ad = -ad;
  if (J < ad || J > j1 + j2) return 0.0;
  double pref = (2.0*J+1.0) * fact(J+j1-j2) * fact(J-j1+j2) * fact(j1+j2-J) / fact(j1+j2+J+1);
  pref *= fact(J+M)*fact(J-M)*fact(j1-m1)*fact(j1+m1)*fact(j2-m2)*fact(j2+m2);
  double s = 0.0;
  for (int k = 0; k <= j1+j2; ++k){
    int d0=j1+j2-J-k, d1=j1-m1-k, d2=j2+m2-k, d3=J-j2+m1+k, d4=J-j1-m2+k;
    if (d0<0||d1<0||d2<0||d3<0||d4<0) continue;
    double t = 1.0/(fact(k)*fact(d0)*fact(d1)*fact(d2)*fact(d3)*fact(d4));
    s += (k & 1) ? -t : t;
  }
  return csqrt(pref) * s;
}
struct C2 { double re, im; };
struct URow { int n; int col[2]; C2 v[2]; };
constexpr URow urow(int l, int r){
  URow u{};
  if (r == l){ u.n = 1; u.col[0] = l; u.v[0] = C2{1.0, 0.0}; return u; }
  if (r > l){
    int m = r - l; double sg = (m & 1) ? -1.0 : 1.0;
    u.n = 2;
    u.col[0] = l + m; u.v[0] = C2{ sg / SQ2, 0.0 };
    u.col[1] = l - m; u.v[1] = C2{ 1.0 / SQ2, 0.0 };
    return u;
  }
  int m = l - r; double sg = (m & 1) ? -1.0 : 1.0;
  u.n = 2;
  u.col[0] = l - m; u.v[0] = C2{ 0.0, 1.0 / SQ2 };
  u.col[1] = l + m; u.v[1] = C2{ 0.0, -sg / SQ2 };
  return u;
}
struct Tab { float v[9][9][9]; };
constexpr Tab build(){
  Tab t{};
  for (int l1 = 0; l1 < 3; ++l1)
  for (int l2 = 0; l2 < 3; ++l2)
  for (int l3 = 0; l3 < 3; ++l3){
    int ad = l1 - l2; if (ad < 0) ad = -ad;
    if (l3 < ad || l3 > l1 + l2) continue;
    double C[5][5][5] = {};
    for (int m = 0; m < 2*l1+1; ++m)
      for (int n = 0; n < 2*l2+1; ++n){
        int o = (m - l1) + (n - l2) + l3;
        if (o < 0 || o > 2*l3) continue;
        C[m][n][o] = cgc(l1, m-l1, l2, n-l2, l3, o-l3);
      }
    for (int a = 0; a < 2*l1+1; ++a)
    for (int b = 0; b < 2*l2+1; ++b)
    for (int c = 0; c < 2*l3+1; ++c){
      URow ua = urow(l1,a), ub = urow(l2,b), uc = urow(l3,c);
      double gre = 0.0, gim = 0.0;
      for (int i = 0; i < ua.n; ++i)
      for (int j = 0; j < ub.n; ++j)
      for (int k = 0; k < uc.n; ++k){
        double Cv = C[ua.col[i]][ub.col[j]][uc.col[k]];
        if (Cv == 0.0) continue;
        double r1 = ua.v[i].re*ub.v[j].re - ua.v[i].im*ub.v[j].im;
        double i1 = ua.v[i].re*ub.v[j].im + ua.v[i].im*ub.v[j].re;
        double cr = uc.v[k].re, ci = -uc.v[k].im;
        gre += (r1*cr - i1*ci) * Cv;
        gim += (r1*ci + i1*cr) * Cv;
      }
      double r = (cabs_(gim) > cabs_(gre)) ? gim : gre;
      t.v[l1*l1+a][l2*l2+b][l3*l3+c] = (float)r;
    }
  }
  return t;
}
constexpr Tab CGT = build();
} // namespace cgb

constexpr int DM_[9] = {0,1,1,1,2,2,2,2,2};

// ---------------- compile-time for-each --------------------------------------
template<class F, int... Is>
__device__ __forceinline__ void sf_impl(F&& f, std::integer_sequence<int, Is...>){
  (f(std::integral_constant<int, Is>{}), ...);
}
template<int N, class F>
__device__ __forceinline__ void static_for(F&& f){
  sf_impl(static_cast<F&&>(f), std::make_integer_sequence<int, N>{});
}

// ---------------- device helpers ---------------------------------------------
__device__ __forceinline__ float rsum32(float v){
  #pragma unroll
  for (int s = 16; s > 0; s >>= 1) v += __shfl_xor(v, s, 32);
  return v;
}

__device__ __forceinline__ float dot32_lds(const float* sm, int xrow_off,
                                           const float (&wcol)[32]){
  float acc = 0.f;
  #pragma unroll
  for (int i = 0; i < 8; ++i){
    float4 xv = *reinterpret_cast<const float4*>(&sm[xrow_off + 4*i]);
    acc = fmaf(xv.x, wcol[4*i+0], acc);
    acc = fmaf(xv.y, wcol[4*i+1], acc);
    acc = fmaf(xv.z, wcol[4*i+2], acc);
    acc = fmaf(xv.w, wcol[4*i+3], acc);
  }
  return acc;
}

// Dense over comps m = hg, hg+8, hg+16(<18); W column from global. hg in [0,8).
__device__ __forceinline__ void dense_hg(float* sm, int xoff,
                                         const float* __restrict__ W,
                                         int ooff, int f, int hg){
  float wcol[32];
  #pragma unroll
  for (int fp = 0; fp < 32; ++fp) wcol[fp] = W[fp*32 + f];
  for (int m = hg; m < 18; m += 8)
    sm[ooff + m*32 + f] = dot32_lds(sm, xoff + m*32, wcol);
}

// Fused dense + bias@comp0 + silu (per-thread gate recompute, bit-identical).
__device__ __forceinline__ void dense_silu_hg(float* sm, int xoff,
                                              const float* __restrict__ W,
                                              const float* __restrict__ bias,
                                              int ooff, int f, int hg){
  float wcol[32];
  #pragma unroll
  for (int fp = 0; fp < 32; ++fp) wcol[fp] = W[fp*32 + f];
  float acc0 = dot32_lds(sm, xoff, wcol);
  float b = bias[f];
  float gate = 1.f / (1.f + expf(-(acc0 + b)));
  for (int m = hg; m < 18; m += 8){
    float acc = (m == 0) ? (acc0 + b) : dot32_lds(sm, xoff + m*32, wcol);
    sm[ooff + m*32 + f] = acc * gate;
  }
}

// Distributed couple: wave wv computes comps c%4==wv; half q computes parity q.
// OUTMODE 0: sm[dsto+row] = out + sm[addo+row]; if (efo>=0) sm[efo+row] = out
// OUTMODE 1: r = out + sm[addo+row]; gout[row] = r; sm[xoo+row] = r
// OUTMODE 3: rows {0(q0),1..3(q1)} -> sm[dsto + slot*32+f] = out + sm[addo+row]
template<int OUTMODE>
__device__ __forceinline__ void couple_stage(float* sm, int x1o, int x2o,
                                             const float* __restrict__ Wp,
                                             int dsto, int addo,
                                             float* gout, int efo, int xoo,
                                             int f, int wv, int q){
  int r2a = x2o + q*9*32 + f;
  int r2b = x2o + (q^1)*9*32 + f;
  static_for<9>([&](auto C){
    constexpr int c = C.value;
    if ((c & 3) == wv){
      bool need = true;
      if constexpr (OUTMODE == 3) need = q ? (c >= 1 && c <= 3) : (c == 0);
      if (need){
        float out = 0.f;
        static_for<81>([&](auto AB){
          constexpr int a = AB.value / 9, b = AB.value % 9;
          constexpr float v = cgb::CGT.v[a][b][c];
          if constexpr (v != 0.0f){
            constexpr int path = (DM_[a]*3 + DM_[b])*3 + DM_[c];
            float w   = v * Wp[path*32 + f];
            float x10 = sm[x1o + a*32 + f];
            float x11 = sm[x1o + (9+a)*32 + f];
            out = fmaf(w, fmaf(x10, sm[r2a + b*32], x11*sm[r2b + b*32]), out);
          }
        });
        int row = (q*9 + c)*32 + f;
        if constexpr (OUTMODE == 0){
          sm[dsto + row] = out + sm[addo + row];
          if (efo >= 0) sm[efo + row] = out;
        }
        if constexpr (OUTMODE == 1){
          float r = out + sm[addo + row];
          gout[row] = r;
          sm[xoo + row] = r;
        }
        if constexpr (OUTMODE == 3){
          int slot = q ? c : 0;
          sm[dsto + slot*32 + f] = out + sm[addo + row];
        }
      }
    }
  });
}

// ---------------- LDS layout (word offsets) — 5968 words = 23.9 KB ------------
#define L_WL   0      /* 768: Wmp (per-iter reload) */
#define L_GEO  768    /* 31*19 = 589: sh[9], rad[8], srcid (stride 19) */
#define L_XB   1360   /* 576 */
#define L_EB   1936   /* 576: xEF — lives here across all iterations */
#define L_YB   2512   /* 576 */
#define L_XO   3088   /* 576: own-node X (previous iteration) */
#define L_RED  3664   /* 4*576 = 2304: msg partials; then x2/TBU/TBV; EBnew */
#define L_TOT  5968
// head / final-phase sub-buffers inside L_RED (dead regions by then):
#define L_HA   (L_RED)
#define L_HB   (L_RED + 128)
#define L_TU   (L_RED + 256)
#define L_TV   (L_RED + 384)
#define L_EBN  (L_RED + 1728)   /* new xEF from couple<0> */

#define NBLK 1024

struct KParams {
  const float* POS; const int* Z; const float* Ef;
  const int* src; const int* dst;
  const float* embed;
  const float* Wmp; const float* Wd; const float* bd;
  const float* Wt; const float* Wtd1; const float* Wtd2; const float* Wtdp;
  const float* Wh; const float* bh; const float* Wq;
  const float* Wdip1; const float* Wdip2; const float* Wdipp; const float* wdip;
  const float* We; const float* be; const float* ebias;
  float* Xa; float* Xb;
  float* Q; float* AE; float* AD;
  float* out;
  int* cnt; int* gen;
};

// Device-scope barrier across all NBLK co-resident blocks.
__device__ __forceinline__ void grid_barrier(int* cnt, int* gen){
  __syncthreads();
  if (threadIdx.x == 0){
    __threadfence();   // write back this XCD's dirty L2 lines (X/Q/AE/AD rows)
    int g = __hip_atomic_load(gen, __ATOMIC_RELAXED, __HIP_MEMORY_SCOPE_AGENT);
    int v = __hip_atomic_fetch_add(cnt, 1, __ATOMIC_ACQ_REL, __HIP_MEMORY_SCOPE_AGENT);
    if (v == NBLK - 1){
      __hip_atomic_store(cnt, 0, __ATOMIC_RELAXED, __HIP_MEMORY_SCOPE_AGENT);
      __hip_atomic_fetch_add(gen, 1, __ATOMIC_ACQ_REL, __HIP_MEMORY_SCOPE_AGENT);
    } else {
      while (__hip_atomic_load(gen, __ATOMIC_ACQUIRE, __HIP_MEMORY_SCOPE_AGENT) == g){
        __builtin_amdgcn_s_sleep(2);
      }
    }
    __threadfence();   // invalidate stale lines before reading others' writes
  }
  __syncthreads();
}

// One message-pass + node-update iteration. MODE 0: first (x=embed pattern,
// xEF=Ef pattern). MODE 1: middle. MODE 2: last (md=0) + fused 4-comp head.
template<int MODE>
__device__ __forceinline__ void iter_body(float* sm, const KParams& p,
    const float* Wmp_i, const float* Wd_i, const float* bd_i, const float* Wt_i,
    const float* Wtd1_i, const float* Wtd2_i, const float* Wtdp_i,
    const float* Xprev, float* Xout,
    int n, int bi, int d, int f, int hg, int wv, int q, int tid)
{
  for (int j = tid; j < 768; j += 256) sm[L_WL+j] = Wmp_i[j];
  if constexpr (MODE == 0){
    float e3[3] = { p.Ef[bi*3+0], p.Ef[bi*3+1], p.Ef[bi*3+2] };
    for (int j2 = tid; j2 < 576; j2 += 256){
      int m = (j2 >> 5) % 9;
      sm[L_EB + j2] = (m >= 1 && m <= 3) ? e3[m-1] : 0.f;
    }
  }
  __syncthreads();                                         // B1

  // ---- message pass: half-group hg handles edges t = hg+8k (t<31) ----
  float acc[2][9];
  #pragma unroll
  for (int pp = 0; pp < 2; ++pp)
    #pragma unroll
    for (int c = 0; c < 9; ++c) acc[pp][c] = 0.0f;

  #pragma unroll
  for (int k = 0; k < 4; ++k){
    int t = hg + 8*k;
    if (t < 31){
      const float* gp = &sm[L_GEO + t*19];
      float wt0 = 0.f, wt1 = 0.f, wt2 = 0.f;
      #pragma unroll
      for (int nb = 0; nb < 8; ++nb){
        float rv = gp[9+nb];
        wt0 = fmaf(rv, sm[L_WL + (0*8+nb)*32 + f], wt0);
        wt1 = fmaf(rv, sm[L_WL + (1*8+nb)*32 + f], wt1);
        wt2 = fmaf(rv, sm[L_WL + (2*8+nb)*32 + f], wt2);
      }
      float g[9];
      g[0] = gp[0]*wt0;
      g[1] = gp[1]*wt1; g[2] = gp[2]*wt1; g[3] = gp[3]*wt1;
      g[4] = gp[4]*wt2; g[5] = gp[5]*wt2; g[6] = gp[6]*wt2;
      g[7] = gp[7]*wt2; g[8] = gp[8]*wt2;
      int s = __float_as_int(gp[18]);

      if constexpr (MODE == 0){
        float x00 = p.embed[p.Z[s]*32 + f];
        static_for<9>([&](auto C){
          constexpr int c = C.value;
          constexpr int pb = DM_[c] & 1;
          acc[pb][c] = fmaf(g[c], x00, acc[pb][c]);
        });
      } else {
        const float* xp = Xprev + (size_t)s*576 + f;
        static_for<9>([&](auto A){
          constexpr int a = A.value;
          float x0a = xp[a*32];
          float x1a = xp[(9+a)*32];
          static_for<81>([&](auto BC){
            constexpr int b = BC.value / 9, c = BC.value % 9;
            constexpr float v = cgb::CGT.v[a][b][c];
            if constexpr (v != 0.0f){
              constexpr int pb = DM_[b] & 1;
              float tg = v * g[b];
              acc[0][c] = fmaf(tg, pb ? x1a : x0a, acc[0][c]);
              acc[1][c] = fmaf(tg, pb ? x0a : x1a, acc[1][c]);
            }
          });
        });
      }
    }
  }
  #pragma unroll
  for (int pp = 0; pp < 2; ++pp)
    #pragma unroll
    for (int c = 0; c < 9; ++c) acc[pp][c] += __shfl_xor(acc[pp][c], 32);
  if ((tid & 63) < 32){
    #pragma unroll
    for (int pp = 0; pp < 2; ++pp)
      #pragma unroll
      for (int c = 0; c < 9; ++c) sm[L_RED + wv*576 + (pp*9+c)*32 + f] = acc[pp][c];
  }
  __syncthreads();                                         // B2

  // ---- stage A: y = sum of partials (mask at MODE2), XB = silu(x + y) ----
  {
    int zn = 0;
    if constexpr (MODE == 0) zn = p.Z[n];
    for (int j2 = tid; j2 < 576; j2 += 256){
      int jm = (j2 >> 5) % 9;
      int ff = j2 & 31;
      float y = sm[L_RED+j2] + sm[L_RED+576+j2] + sm[L_RED+1152+j2] + sm[L_RED+1728+j2];
      if (MODE == 2 && jm != 0) y = 0.f;
      float y0 = sm[L_RED+ff] + sm[L_RED+576+ff] + sm[L_RED+1152+ff] + sm[L_RED+1728+ff];
      float xv, x0;
      if constexpr (MODE == 0){
        xv = (j2 < 32) ? p.embed[zn*32 + j2] : 0.f;
        x0 = p.embed[zn*32 + ff];
      } else {
        xv = sm[L_XO + j2];
        x0 = sm[L_XO + ff];
      }
      float gate = 1.f / (1.f + expf(-(x0 + y0)));
      sm[L_YB + j2] = y;
      sm[L_XB + j2] = (xv + y) * gate;
    }
  }
  __syncthreads();                                         // B3

  // fused dense(Wd) + bias + silu -> L_RED (x2)
  dense_silu_hg(sm, L_XB, Wd_i, bd_i, L_RED, f, hg);
  __syncthreads();                                         // B4

  // couple(x2, xEF, Wt): XB = x2 + coupled; EBnew = coupled (MODE<2)
  couple_stage<0>(sm, L_RED, L_EB, Wt_i, L_XB, L_RED,
                  nullptr, (MODE < 2) ? L_EBN : -1, -1, f, wv, q);
  __syncthreads();                                         // B5

  // EB = EBnew (MODE<2) alongside tensor-dense u,v
  if constexpr (MODE < 2){
    for (int j2 = tid; j2 < 576; j2 += 256) sm[L_EB + j2] = sm[L_EBN + j2];
  }
  dense_hg(sm, L_XB, Wtd1_i, L_RED + 576,  f, hg);         // u -> TBU
  dense_hg(sm, L_XB, Wtd2_i, L_RED + 1152, f, hg);         // v -> TBV
  __syncthreads();                                         // B6

  if constexpr (MODE < 2){
    couple_stage<1>(sm, L_RED + 576, L_RED + 1152, Wtdp_i, 0, L_YB,
                    Xout + (size_t)n*576, -1, L_XO, f, wv, q);
    return;
  } else {
    couple_stage<3>(sm, L_RED + 576, L_RED + 1152, Wtdp_i, L_HA, L_YB,
                    nullptr, -1, -1, f, wv, q);
  }
  __syncthreads();                                         // B7 (MODE2)

  // ---- fused 4-comp head: slots {0,1,2,3} = comps {0,10,11,12} ----
  #pragma unroll
  for (int k = 0; k < 5; ++k){
    int srco = (k & 1) ? L_HB : L_HA;
    int dsto = (k & 1) ? L_HA : L_HB;
    if (hg < 4){
      float wcol[32];
      #pragma unroll
      for (int fp = 0; fp < 32; ++fp) wcol[fp] = p.Wh[k*1024 + fp*32 + f];
      float acc0 = dot32_lds(sm, srco, wcol);
      float b = p.bh[k*32 + f];
      float accr = (hg == 0) ? acc0 : dot32_lds(sm, srco + hg*32, wcol);
      float val = accr + ((hg == 0) ? b : 0.f);
      if (k < 4) val *= 1.f / (1.f + expf(-(acc0 + b)));
      sm[dsto + hg*32 + f] = val;
    }
    __syncthreads();
  }
  // final head x in L_HB

  if (hg < 8){
    int mat = hg >> 2;
    int slot = hg & 3;
    const float* W = mat ? p.Wdip2 : p.Wdip1;
    float wcol[32];
    #pragma unroll
    for (int fp = 0; fp < 32; ++fp) wcol[fp] = W[fp*32 + f];
    float acc2 = dot32_lds(sm, L_HB + slot*32, wcol);
    sm[(mat ? L_TV : L_TU) + slot*32 + f] = acc2;
  }
  __syncthreads();

  if (tid < 32){
    float scal = sm[L_HB + f];
    float qv = rsum32(scal * p.Wq[f]);
    float ae = rsum32(scal * p.We[f]) + p.be[0] + p.ebias[p.Z[n]];
    float u00 = sm[L_TU + f], v00 = sm[L_TV + f];
    float wp4  = p.Wdipp[4*32 + f];    // path (0,1,1)
    float wp10 = p.Wdipp[10*32 + f];   // path (1,0,1)
    float wd = p.wdip[f];
    float ad[3];
    #pragma unroll
    for (int c = 1; c <= 3; ++c){
      float p1 = wp4*u00*sm[L_TV + c*32 + f] + wp10*sm[L_TU + c*32 + f]*v00;
      ad[c-1] = rsum32(p1 * wd);
    }
    if (f == 0){
      p.Q[n] = qv;
      p.AE[n] = ae;
      p.AD[3*n+0] = ad[0]; p.AD[3*n+1] = ad[1]; p.AD[3*n+2] = ad[2];
    }
  }
}

// The whole network in one launch.
__global__ __launch_bounds__(256, 4) void k_all(KParams p){
  __shared__ __align__(16) float sm[L_TOT];
  const int tid = threadIdx.x;
  const int f = tid & 31, hg = tid >> 5, wv = tid >> 6, q = (tid >> 5) & 1;
  // XCD-aware swizzle: same-XCD blocks get whole graphs.
  const int n = ((blockIdx.x & 7) << 7) | (blockIdx.x >> 3);
  const int bi = n >> 5, d = n & 31;

  // ---- one-time edge geometry into LDS (stride 19: conflict-free writes) ----
  if (tid < 31){
    int t = tid;
    int s = bi*32 + p.src[d*31 + t];
    float dx = p.POS[s*3+0] - p.POS[n*3+0];
    float dy = p.POS[s*3+1] - p.POS[n*3+1];
    float dz = p.POS[s*3+2] - p.POS[n*3+2];
    float r  = sqrtf(dx*dx + dy*dy + dz*dz);
    float inv = 1.0f / (r + 1e-10f);
    float x = dx*inv, y = dy*inv, z = dz*inv;
    const float s3 = 1.7320508075688772f;
    float* gp = &sm[L_GEO + t*19];
    gp[0] = 1.0f; gp[1] = y; gp[2] = z; gp[3] = x;
    gp[4] = s3*x*y; gp[5] = s3*y*z; gp[6] = 0.5f*(3.0f*z*z - 1.0f);
    gp[7] = s3*x*z; gp[8] = 0.5f*s3*(x*x - y*y);
    float fr = 1.0f / (1.0f + r);
    float om = 1.0f - fr;
    float frk[8]; frk[0] = 1.0f;
    #pragma unroll
    for (int kk = 1; kk < 8; ++kk) frk[kk] = frk[kk-1]*fr;
    float omk[8]; omk[0] = 1.0f;
    #pragma unroll
    for (int kk = 1; kk < 8; ++kk) omk[kk] = omk[kk-1]*om;
    const float bin[8] = {1.f,7.f,21.f,35.f,35.f,21.f,7.f,1.f};
    float u2 = (r*0.2f)*(r*0.2f);
    float cut = 0.0f;
    if (r < 5.0f){
      float den = fmaxf(1.0f - u2, 1e-6f);
      cut = expf(1.0f - 1.0f/den);
    }
    #pragma unroll
    for (int kk = 0; kk < 8; ++kk) gp[9+kk] = bin[kk]*frk[kk]*omk[7-kk]*cut;
    gp[18] = __int_as_float(s);
  }
  // no explicit sync needed: iter_body<0>'s B1 covers GEO visibility

  iter_body<0>(sm, p, p.Wmp,        p.Wd,        p.bd,      p.Wt,
               p.Wtd1,        p.Wtd2,        p.Wtdp,
               nullptr, p.Xa, n, bi, d, f, hg, wv, q, tid);
  grid_barrier(p.cnt, p.gen);

  iter_body<1>(sm, p, p.Wmp + 768,  p.Wd + 1024, p.bd + 32, p.Wt + 864,
               p.Wtd1 + 1024, p.Wtd2 + 1024, p.Wtdp + 864,
               p.Xa, p.Xb, n, bi, d, f, hg, wv, q, tid);
  grid_barrier(p.cnt, p.gen);

  iter_body<2>(sm, p, p.Wmp + 1536, p.Wd + 2048, p.bd + 64, p.Wt + 1728,
               p.Wtd1 + 2048, p.Wtd2 + 2048, p.Wtdp + 1728,
               p.Xb, nullptr, n, bi, d, f, hg, wv, q, tid);
  grid_barrier(p.cnt, p.gen);

  // ---- fused per-graph reduction: one block per graph (d == 0) ----
  if (d == 0){
    float qv = 0.f, ae = 0.f, px = 0.f, py = 0.f, pz = 0.f;
    float ax = 0.f, ay = 0.f, az = 0.f;
    if (tid < 32){
      int nn = bi*32 + tid;
      qv = p.Q[nn]; ae = p.AE[nn];
      px = p.POS[nn*3+0]; py = p.POS[nn*3+1]; pz = p.POS[nn*3+2];
      ax = p.AD[3*nn+0]; ay = p.AD[3*nn+1]; az = p.AD[3*nn+2];
      sm[L_RED + tid]      = qv;
      sm[L_RED + 32 + tid] = px;
      sm[L_RED + 64 + tid] = py;
      sm[L_RED + 96 + tid] = pz;
    }
    __syncthreads();
    float sae = 0.f, dipx = 0.f, dipy = 0.f, dipz = 0.f;
    if (tid < 32){
      const float invN = 1.0f / 32.0f;
      float cx = rsum32(px) * invN;
      float cy = rsum32(py) * invN;
      float cz = rsum32(pz) * invN;
      dipx = rsum32(qv*(px - cx) + ax);
      dipy = rsum32(qv*(py - cy) + ay);
      dipz = rsum32(qv*(pz - cz) + az);
      sae  = rsum32(ae);
    }
    // Coulomb over this graph's 992 edges, all 256 threads
    float cl = 0.0f;
    for (int e = tid; e < 992; e += 256){
      int dd = p.dst[e], ss = p.src[e];
      float dx = sm[L_RED+32+ss] - sm[L_RED+32+dd];
      float dy = sm[L_RED+64+ss] - sm[L_RED+64+dd];
      float dz = sm[L_RED+96+ss] - sm[L_RED+96+dd];
      float r = sqrtf(dx*dx + dy*dy + dz*dz);
      cl += sm[L_RED+ss]*sm[L_RED+dd] / (r + 1e-10f);
    }
    #pragma unroll
    for (int s = 32; s > 0; s >>= 1) cl += __shfl_xor(cl, s, 64);
    if ((tid & 63) == 0) sm[L_RED + 128 + wv] = cl;
    __syncthreads();
    if (tid == 0){
      float clt = sm[L_RED+128] + sm[L_RED+129] + sm[L_RED+130] + sm[L_RED+131];
      p.out[bi] = sae + 0.5f*clt*14.399645f;
      p.out[32 + bi*3 + 0] = dipx;
      p.out[32 + bi*3 + 1] = dipy;
      p.out[32 + bi*3 + 2] = dipz;
    }
  }
}

// ---------------- host launcher -----------------------------------------------
extern "C" void kernel_launch(void* const* d_in, const int* in_sizes, int n_in,
                              void* d_out, int out_size, void* d_ws, size_t ws_size,
                              hipStream_t stream) {
  (void)n_in; (void)out_size; (void)ws_size;
  const int*   Z     = (const int*)  d_in[0];
  const float* POS   = (const float*)d_in[1];
  const float* Ef    = (const float*)d_in[2];
  const int*   dst   = (const int*)  d_in[3];
  const int*   src   = (const int*)  d_in[4];
  const float* embed = (const float*)d_in[6];
  const float* Wmp   = (const float*)d_in[7];
  const float* Wd    = (const float*)d_in[8];
  const float* bd    = (const float*)d_in[9];
  const float* Wt    = (const float*)d_in[10];
  const float* Wtd1  = (const float*)d_in[11];
  const float* Wtd2  = (const float*)d_in[12];
  const float* Wtdp  = (const float*)d_in[13];
  const float* Wh    = (const float*)d_in[14];
  const float* bh    = (const float*)d_in[15];
  const float* Wq    = (const float*)d_in[16];
  const float* Wdip1 = (const float*)d_in[17];
  const float* Wdip2 = (const float*)d_in[18];
  const float* Wdipp = (const float*)d_in[19];
  const float* wdip  = (const float*)d_in[20];
  const float* We    = (const float*)d_in[21];
  const float* be    = (const float*)d_in[22];
  const float* ebias = (const float*)d_in[23];

  const int BN = in_sizes[0];        // 1024

  float* wsf = (float*)d_ws;
  float* Xa  = wsf;
  float* Xb  = Xa  + (size_t)BN*576;
  float* Qb  = Xb  + (size_t)BN*576;
  float* AEb = Qb  + BN;
  float* AD  = AEb + BN;
  int*   cnt = (int*)(AD + 3*BN);
  int*   gen = cnt + 1;

  // deterministic barrier state each call (ws is poisoned once, never restored)
  hipMemsetAsync((void*)cnt, 0, 2*sizeof(int), stream);

  KParams p{};
  p.POS = POS; p.Z = Z; p.Ef = Ef; p.src = src; p.dst = dst; p.embed = embed;
  p.Wmp = Wmp; p.Wd = Wd; p.bd = bd; p.Wt = Wt;
  p.Wtd1 = Wtd1; p.Wtd2 = Wtd2; p.Wtdp = Wtdp;
  p.Wh = Wh; p.bh = bh; p.Wq = Wq;
  p.Wdip1 = Wdip1; p.Wdip2 = Wdip2; p.Wdipp = Wdipp; p.wdip = wdip;
  p.We = We; p.be = be; p.ebias = ebias;
  p.Xa = Xa; p.Xb = Xb;
  p.Q = Qb; p.AE = AEb; p.AD = AD;
  p.out = (float*)d_out;
  p.cnt = cnt; p.gen = gen;

  k_all<<<NBLK, 256, 0, stream>>>(p);
}

// Round 11
// 85.233 us; speedup vs baseline: 9.2737x; 9.2737x over previous
//
#include <hip/hip_runtime.h>
#include <utility>
#include <type_traits>

// ============================================================================
// Equivariant MPNN forward (B=32, N=32, F=32, 9 comps, 2 parities, 3 iters)
// R11 = R8 (best: 89.6us) + edge geometry staged in LDS once per block
// (stride 19, conflict-free), computed by 31 threads overlapped with weight
// loads. R9/R10 structural experiments reverted (both regressed).
// Sizes hardcoded: Nn=32, Eb=992, B=32, F=32.
// ============================================================================

// ---------------- compile-time CG table (exact port of _build_cg) ----------
namespace cgb {
constexpr double SQ2 = 1.4142135623730951;
constexpr double cabs_(double x){ return x < 0 ? -x : x; }
constexpr double fact(int n){ double r = 1.0; for (int i = 2; i <= n; ++i) r *= (double)i; return r; }
constexpr double csqrt(double x){
  if (x <= 0.0) return 0.0;
  double g = x > 1.0 ? x : 1.0;
  for (int i = 0; i < 48; ++i) g = 0.5 * (g + x / g);
  return g;
}
constexpr double cgc(int j1,int m1,int j2,int m2,int J,int M){
  if (m1 + m2 != M) return 0.0;
  int ad = j1 - j2; if (ad < 0) ad = -ad;
  if (J < ad || J > j1 + j2) return 0.0;
  double pref = (2.0*J+1.0) * fact(J+j1-j2) * fact(J-j1+j2) * fact(j1+j2-J) / fact(j1+j2+J+1);
  pref *= fact(J+M)*fact(J-M)*fact(j1-m1)*fact(j1+m1)*fact(j2-m2)*fact(j2+m2);
  double s = 0.0;
  for (int k = 0; k <= j1+j2; ++k){
    int d0=j1+j2-J-k, d1=j1-m1-k, d2=j2+m2-k, d3=J-j2+m1+k, d4=J-j1-m2+k;
    if (d0<0||d1<0||d2<0||d3<0||d4<0) continue;
    double t = 1.0/(fact(k)*fact(d0)*fact(d1)*fact(d2)*fact(d3)*fact(d4));
    s += (k & 1) ? -t : t;
  }
  return csqrt(pref) * s;
}
struct C2 { double re, im; };
struct URow { int n; int col[2]; C2 v[2]; };
constexpr URow urow(int l, int r){
  URow u{};
  if (r == l){ u.n = 1; u.col[0] = l; u.v[0] = C2{1.0, 0.0}; return u; }
  if (r > l){
    int m = r - l; double sg = (m & 1) ? -1.0 : 1.0;
    u.n = 2;
    u.col[0] = l + m; u.v[0] = C2{ sg / SQ2, 0.0 };
    u.col[1] = l - m; u.v[1] = C2{ 1.0 / SQ2, 0.0 };
    return u;
  }
  int m = l - r; double sg = (m & 1) ? -1.0 : 1.0;
  u.n = 2;
  u.col[0] = l - m; u.v[0] = C2{ 0.0, 1.0 / SQ2 };
  u.col[1] = l + m; u.v[1] = C2{ 0.0, -sg / SQ2 };
  return u;
}
struct Tab { float v[9][9][9]; };
constexpr Tab build(){
  Tab t{};
  for (int l1 = 0; l1 < 3; ++l1)
  for (int l2 = 0; l2 < 3; ++l2)
  for (int l3 = 0; l3 < 3; ++l3){
    int ad = l1 - l2; if (ad < 0) ad = -ad;
    if (l3 < ad || l3 > l1 + l2) continue;
    double C[5][5][5] = {};
    for (int m = 0; m < 2*l1+1; ++m)
      for (int n = 0; n < 2*l2+1; ++n){
        int o = (m - l1) + (n - l2) + l3;
        if (o < 0 || o > 2*l3) continue;
        C[m][n][o] = cgc(l1, m-l1, l2, n-l2, l3, o-l3);
      }
    for (int a = 0; a < 2*l1+1; ++a)
    for (int b = 0; b < 2*l2+1; ++b)
    for (int c = 0; c < 2*l3+1; ++c){
      URow ua = urow(l1,a), ub = urow(l2,b), uc = urow(l3,c);
      double gre = 0.0, gim = 0.0;
      for (int i = 0; i < ua.n; ++i)
      for (int j = 0; j < ub.n; ++j)
      for (int k = 0; k < uc.n; ++k){
        double Cv = C[ua.col[i]][ub.col[j]][uc.col[k]];
        if (Cv == 0.0) continue;
        double r1 = ua.v[i].re*ub.v[j].re - ua.v[i].im*ub.v[j].im;
        double i1 = ua.v[i].re*ub.v[j].im + ua.v[i].im*ub.v[j].re;
        double cr = uc.v[k].re, ci = -uc.v[k].im;
        gre += (r1*cr - i1*ci) * Cv;
        gim += (r1*ci + i1*cr) * Cv;
      }
      double r = (cabs_(gim) > cabs_(gre)) ? gim : gre;
      t.v[l1*l1+a][l2*l2+b][l3*l3+c] = (float)r;
    }
  }
  return t;
}
constexpr Tab CGT = build();
} // namespace cgb

constexpr int DM_[9] = {0,1,1,1,2,2,2,2,2};

// ---------------- compile-time for-each --------------------------------------
template<class F, int... Is>
__device__ __forceinline__ void sf_impl(F&& f, std::integer_sequence<int, Is...>){
  (f(std::integral_constant<int, Is>{}), ...);
}
template<int N, class F>
__device__ __forceinline__ void static_for(F&& f){
  sf_impl(static_cast<F&&>(f), std::make_integer_sequence<int, N>{});
}

// ---------------- device helpers ---------------------------------------------
__device__ __forceinline__ float rsum32(float v){
  #pragma unroll
  for (int s = 16; s > 0; s >>= 1) v += __shfl_xor(v, s, 32);
  return v;
}

__device__ __forceinline__ float dot32_lds(const float* sm, int xrow_off,
                                           const float (&wcol)[32]){
  float acc = 0.f;
  #pragma unroll
  for (int i = 0; i < 8; ++i){
    float4 xv = *reinterpret_cast<const float4*>(&sm[xrow_off + 4*i]);
    acc = fmaf(xv.x, wcol[4*i+0], acc);
    acc = fmaf(xv.y, wcol[4*i+1], acc);
    acc = fmaf(xv.z, wcol[4*i+2], acc);
    acc = fmaf(xv.w, wcol[4*i+3], acc);
  }
  return acc;
}

// Dense over comps m = hg, hg+8, hg+16(<18); W column from global. hg in [0,8).
__device__ __forceinline__ void dense_hg(float* sm, int xoff,
                                         const float* __restrict__ W,
                                         int ooff, int f, int hg){
  float wcol[32];
  #pragma unroll
  for (int fp = 0; fp < 32; ++fp) wcol[fp] = W[fp*32 + f];
  for (int m = hg; m < 18; m += 8)
    sm[ooff + m*32 + f] = dot32_lds(sm, xoff + m*32, wcol);
}

// Fused dense + bias@comp0 + silu (per-thread gate recompute, bit-identical).
__device__ __forceinline__ void dense_silu_hg(float* sm, int xoff,
                                              const float* __restrict__ W,
                                              const float* __restrict__ bias,
                                              int ooff, int f, int hg){
  float wcol[32];
  #pragma unroll
  for (int fp = 0; fp < 32; ++fp) wcol[fp] = W[fp*32 + f];
  float acc0 = dot32_lds(sm, xoff, wcol);
  float b = bias[f];
  float gate = 1.f / (1.f + expf(-(acc0 + b)));
  for (int m = hg; m < 18; m += 8){
    float acc = (m == 0) ? (acc0 + b) : dot32_lds(sm, xoff + m*32, wcol);
    sm[ooff + m*32 + f] = acc * gate;
  }
}

// Distributed couple: wave wv computes comps c%4==wv; half q computes parity q.
// Wp read from global (L1-hot 27x32 table).
// OUTMODE 0: sm[dsto+row] = out + sm[addo+row]; if(gef) gef[row] = out
// OUTMODE 1: gout[row]    = out + sm[addo+row]
// OUTMODE 3: rows {0(q0),1..3(q1)} only -> sm[dsto + slot*32+f] = out+sm[addo+row]
template<int OUTMODE>
__device__ __forceinline__ void couple_stage(float* sm, int x1o, int x2o,
                                             const float* __restrict__ Wp,
                                             int dsto, int addo,
                                             float* gout, float* gef,
                                             int f, int wv, int q){
  int r2a = x2o + q*9*32 + f;
  int r2b = x2o + (q^1)*9*32 + f;
  static_for<9>([&](auto C){
    constexpr int c = C.value;
    if ((c & 3) == wv){
      bool need = true;
      if constexpr (OUTMODE == 3) need = q ? (c >= 1 && c <= 3) : (c == 0);
      if (need){
        float out = 0.f;
        static_for<81>([&](auto AB){
          constexpr int a = AB.value / 9, b = AB.value % 9;
          constexpr float v = cgb::CGT.v[a][b][c];
          if constexpr (v != 0.0f){
            constexpr int path = (DM_[a]*3 + DM_[b])*3 + DM_[c];
            float w   = v * Wp[path*32 + f];
            float x10 = sm[x1o + a*32 + f];
            float x11 = sm[x1o + (9+a)*32 + f];
            out = fmaf(w, fmaf(x10, sm[r2a + b*32], x11*sm[r2b + b*32]), out);
          }
        });
        int row = (q*9 + c)*32 + f;
        if constexpr (OUTMODE == 0){
          sm[dsto + row] = out + sm[addo + row];
          if (gef) gef[row] = out;
        }
        if constexpr (OUTMODE == 1) gout[row] = out + sm[addo + row];
        if constexpr (OUTMODE == 3){
          int slot = q ? c : 0;
          sm[dsto + slot*32 + f] = out + sm[addo + row];
        }
      }
    }
  });
}

// ---------------- LDS layout (word offsets) — 5392 words = 21.6 KB ------------
#define L_WL   0      /* 768: Wmp */
#define L_GEO  768    /* 31*19 = 589 (+3 pad): sh[9], rad[8], srcid; stride 19 */
#define L_XB   1360   /* 576 */
#define L_EB   1936   /* 576 */
#define L_YB   2512   /* 576 */
#define L_RED  3088   /* 2304: msg partials; then x2/TBU/TBV */
#define L_TOT  5392
// head sub-buffers inside L_RED's x2 region (dead by then):
#define L_HA   (L_RED)
#define L_HB   (L_RED + 128)
#define L_TU   (L_RED + 256)
#define L_TV   (L_RED + 384)

struct KParams {
  const float* POS; const int* Z; const float* Ef;
  const int* src;
  const float* embed;
  const float* Wmp; const float* Wd; const float* bd;
  const float* Wt; const float* Wtd1; const float* Wtd2; const float* Wtdp;
  const float* Wh; const float* bh; const float* Wq;
  const float* Wdip1; const float* Wdip2; const float* Wdipp; const float* wdip;
  const float* We; const float* be; const float* ebias;
  const float* Xc; float* Xn; float* XEF;
  float* Q; float* AE; float* AD;
};

// MODE 0: first iter (x=embed pattern, xEF=Ef pattern), writes Xn+XEF.
// MODE 1: middle iter, reads Xc/XEF, writes Xn+XEF.
// MODE 2: last iter (md=0) + fused 4-comp readout head; writes Q/AE/AD only.
template<int MODE>
__global__ __launch_bounds__(256) void k_iter(KParams p){
  __shared__ __align__(16) float sm[L_TOT];
  int tid = threadIdx.x;
  int f = tid & 31, hg = tid >> 5, wv = tid >> 6, q = (tid >> 5) & 1;
  // XCD-aware swizzle: same-XCD blocks get whole graphs.
  int n = ((blockIdx.x & 7) << 7) | (blockIdx.x >> 3);
  int bi = n >> 5, d = n & 31;

  // ---- pre-B1: 31 threads compute edge geometry; threads >=32 load the rest --
  if (tid < 31){
    int t = tid;
    int s = bi*32 + p.src[d*31 + t];
    float dx = p.POS[s*3+0] - p.POS[n*3+0];
    float dy = p.POS[s*3+1] - p.POS[n*3+1];
    float dz = p.POS[s*3+2] - p.POS[n*3+2];
    float r  = sqrtf(dx*dx + dy*dy + dz*dz);
    float inv = 1.0f / (r + 1e-10f);
    float x = dx*inv, y = dy*inv, z = dz*inv;
    const float s3 = 1.7320508075688772f;
    float* gp = &sm[L_GEO + t*19];
    gp[0] = 1.0f; gp[1] = y; gp[2] = z; gp[3] = x;
    gp[4] = s3*x*y; gp[5] = s3*y*z; gp[6] = 0.5f*(3.0f*z*z - 1.0f);
    gp[7] = s3*x*z; gp[8] = 0.5f*s3*(x*x - y*y);
    float fr = 1.0f / (1.0f + r);
    float om = 1.0f - fr;
    float frk[8]; frk[0] = 1.0f;
    #pragma unroll
    for (int kk = 1; kk < 8; ++kk) frk[kk] = frk[kk-1]*fr;
    float omk[8]; omk[0] = 1.0f;
    #pragma unroll
    for (int kk = 1; kk < 8; ++kk) omk[kk] = omk[kk-1]*om;
    const float bin[8] = {1.f,7.f,21.f,35.f,35.f,21.f,7.f,1.f};
    float u2 = (r*0.2f)*(r*0.2f);
    float cut = 0.0f;
    if (r < 5.0f){
      float den = fmaxf(1.0f - u2, 1e-6f);
      cut = expf(1.0f - 1.0f/den);
    }
    #pragma unroll
    for (int kk = 0; kk < 8; ++kk) gp[9+kk] = bin[kk]*frk[kk]*omk[7-kk]*cut;
    gp[18] = __int_as_float(s);
  } else if (tid >= 32){
    int t2 = tid - 32;                       // 224 workers
    for (int j = t2; j < 768; j += 224) sm[L_WL+j] = p.Wmp[j];
    if constexpr (MODE == 0){
      float e3[3] = { p.Ef[bi*3+0], p.Ef[bi*3+1], p.Ef[bi*3+2] };
      for (int j2 = t2; j2 < 576; j2 += 224){
        int m = (j2 >> 5) % 9;
        sm[L_EB + j2] = (m >= 1 && m <= 3) ? e3[m-1] : 0.f;
      }
    } else {
      const float* erow = p.XEF + (size_t)n*576;
      for (int j2 = t2; j2 < 576; j2 += 224) sm[L_EB+j2] = erow[j2];
    }
  }
  __syncthreads();                                         // B1

  // ---- message pass: half-group hg handles edges t = hg+8k (t<31) ----
  float acc[2][9];
  #pragma unroll
  for (int pp = 0; pp < 2; ++pp)
    #pragma unroll
    for (int c = 0; c < 9; ++c) acc[pp][c] = 0.0f;

  #pragma unroll
  for (int k = 0; k < 4; ++k){
    int t = hg + 8*k;
    if (t < 31){
      const float* gp = &sm[L_GEO + t*19];
      float wt0 = 0.f, wt1 = 0.f, wt2 = 0.f;
      #pragma unroll
      for (int nb = 0; nb < 8; ++nb){
        float rv = gp[9+nb];
        wt0 = fmaf(rv, sm[L_WL + (0*8+nb)*32 + f], wt0);
        wt1 = fmaf(rv, sm[L_WL + (1*8+nb)*32 + f], wt1);
        wt2 = fmaf(rv, sm[L_WL + (2*8+nb)*32 + f], wt2);
      }
      float g[9];
      g[0] = gp[0]*wt0;
      g[1] = gp[1]*wt1; g[2] = gp[2]*wt1; g[3] = gp[3]*wt1;
      g[4] = gp[4]*wt2; g[5] = gp[5]*wt2; g[6] = gp[6]*wt2;
      g[7] = gp[7]*wt2; g[8] = gp[8]*wt2;
      int s = __float_as_int(gp[18]);

      if constexpr (MODE == 0){
        float x00 = p.embed[p.Z[s]*32 + f];
        static_for<9>([&](auto C){
          constexpr int c = C.value;
          constexpr int pb = DM_[c] & 1;
          acc[pb][c] = fmaf(g[c], x00, acc[pb][c]);
        });
      } else {
        const float* xp = p.Xc + (size_t)s*576 + f;
        static_for<9>([&](auto A){
          constexpr int a = A.value;
          float x0a = xp[a*32];
          float x1a = xp[(9+a)*32];
          static_for<81>([&](auto BC){
            constexpr int b = BC.value / 9, c = BC.value % 9;
            constexpr float v = cgb::CGT.v[a][b][c];
            if constexpr (v != 0.0f){
              constexpr int pb = DM_[b] & 1;
              float tg = v * g[b];
              acc[0][c] = fmaf(tg, pb ? x1a : x0a, acc[0][c]);
              acc[1][c] = fmaf(tg, pb ? x0a : x1a, acc[1][c]);
            }
          });
        });
      }
    }
  }
  #pragma unroll
  for (int pp = 0; pp < 2; ++pp)
    #pragma unroll
    for (int c = 0; c < 9; ++c) acc[pp][c] += __shfl_xor(acc[pp][c], 32);
  if ((tid & 63) < 32){
    #pragma unroll
    for (int pp = 0; pp < 2; ++pp)
      #pragma unroll
      for (int c = 0; c < 9; ++c) sm[L_RED + wv*576 + (pp*9+c)*32 + f] = acc[pp][c];
  }
  __syncthreads();                                         // B2

  // ---- stage A: y = sum of partials (mask at MODE2), XB = silu(x + y) ----
  {
    const float* xrow = (MODE == 0) ? nullptr : (p.Xc + (size_t)n*576);
    int zn = 0;
    if constexpr (MODE == 0) zn = p.Z[n];
    for (int j2 = tid; j2 < 576; j2 += 256){
      int jm = (j2 >> 5) % 9;
      int ff = j2 & 31;
      float y = sm[L_RED+j2] + sm[L_RED+576+j2] + sm[L_RED+1152+j2] + sm[L_RED+1728+j2];
      if (MODE == 2 && jm != 0) y = 0.f;
      float y0 = sm[L_RED+ff] + sm[L_RED+576+ff] + sm[L_RED+1152+ff] + sm[L_RED+1728+ff];
      float xv, x0;
      if constexpr (MODE == 0){
        xv = (j2 < 32) ? p.embed[zn*32 + j2] : 0.f;
        x0 = p.embed[zn*32 + ff];
      } else {
        xv = xrow[j2];
        x0 = xrow[ff];
      }
      float gate = 1.f / (1.f + expf(-(x0 + y0)));
      sm[L_YB + j2] = y;
      sm[L_XB + j2] = (xv + y) * gate;
    }
  }
  __syncthreads();                                         // B3

  // fused dense(Wd) + bias + silu -> L_RED (x2)
  dense_silu_hg(sm, L_XB, p.Wd, p.bd, L_RED, f, hg);
  __syncthreads();                                         // B4

  // couple(x2, xEF, Wt): XB = x2 + coupled; xEF (global) = coupled (MODE<2)
  {
    float* erow = (MODE < 2) ? (p.XEF + (size_t)n*576) : nullptr;
    couple_stage<0>(sm, L_RED, L_EB, p.Wt, L_XB, L_RED, nullptr, erow, f, wv, q);
  }
  __syncthreads();                                         // B5

  dense_hg(sm, L_XB, p.Wtd1, L_RED + 576,  f, hg);         // u -> TBU
  dense_hg(sm, L_XB, p.Wtd2, L_RED + 1152, f, hg);         // v -> TBV
  __syncthreads();                                         // B6

  if constexpr (MODE < 2){
    couple_stage<1>(sm, L_RED + 576, L_RED + 1152, p.Wtdp, 0, L_YB,
                    p.Xn + (size_t)n*576, nullptr, f, wv, q);
    return;
  } else {
    couple_stage<3>(sm, L_RED + 576, L_RED + 1152, p.Wtdp, L_HA, L_YB,
                    nullptr, nullptr, f, wv, q);
  }
  __syncthreads();                                         // B7 (MODE2)

  // ---- fused 4-comp head: slots {0,1,2,3} = comps {0,10,11,12} ----
  #pragma unroll
  for (int k = 0; k < 5; ++k){
    int srco = (k & 1) ? L_HB : L_HA;
    int dsto = (k & 1) ? L_HA : L_HB;
    if (hg < 4){
      float wcol[32];
      #pragma unroll
      for (int fp = 0; fp < 32; ++fp) wcol[fp] = p.Wh[k*1024 + fp*32 + f];
      float acc0 = dot32_lds(sm, srco, wcol);
      float b = p.bh[k*32 + f];
      float accr = (hg == 0) ? acc0 : dot32_lds(sm, srco + hg*32, wcol);
      float val = accr + ((hg == 0) ? b : 0.f);
      if (k < 4) val *= 1.f / (1.f + expf(-(acc0 + b)));
      sm[dsto + hg*32 + f] = val;
    }
    __syncthreads();
  }
  // final head x in L_HB

  // dipole denses: hg<4 -> u rows (Wdip1), hg in [4,8) -> v rows (Wdip2)
  {
    int mat = hg >> 2;
    int slot = hg & 3;
    const float* W = mat ? p.Wdip2 : p.Wdip1;
    float wcol[32];
    #pragma unroll
    for (int fp = 0; fp < 32; ++fp) wcol[fp] = W[fp*32 + f];
    float acc2 = dot32_lds(sm, L_HB + slot*32, wcol);
    sm[(mat ? L_TV : L_TU) + slot*32 + f] = acc2;
  }
  __syncthreads();

  if (tid < 32){
    float scal = sm[L_HB + f];
    float qv = rsum32(scal * p.Wq[f]);
    float ae = rsum32(scal * p.We[f]) + p.be[0] + p.ebias[p.Z[n]];
    float u00 = sm[L_TU + f], v00 = sm[L_TV + f];
    float wp4  = p.Wdipp[4*32 + f];    // path (0,1,1)
    float wp10 = p.Wdipp[10*32 + f];   // path (1,0,1)
    float wd = p.wdip[f];
    float ad[3];
    #pragma unroll
    for (int c = 1; c <= 3; ++c){
      float p1 = wp4*u00*sm[L_TV + c*32 + f] + wp10*sm[L_TU + c*32 + f]*v00;
      ad[c-1] = rsum32(p1 * wd);
    }
    if (f == 0){
      p.Q[n] = qv;
      p.AE[n] = ae;
      p.AD[3*n+0] = ad[0]; p.AD[3*n+1] = ad[1]; p.AD[3*n+2] = ad[2];
    }
  }
}

// Per-batch reduction: energy (+ Coulomb, r recomputed from POS) and dipole.
__global__ __launch_bounds__(64) void k_final(const float* __restrict__ Q,
                                              const float* __restrict__ AE,
                                              const float* __restrict__ AD,
                                              const float* __restrict__ POS,
                                              const int* __restrict__ dst_idx,
                                              const int* __restrict__ src_idx,
                                              float* __restrict__ out,
                                              int Nn, int Eb, int Bv){
  __shared__ float qs[32];
  __shared__ float ps[32][3];
  int b = blockIdx.x, tid = threadIdx.x;
  float q = 0.f, ae = 0.f, px = 0.f, py = 0.f, pz = 0.f, ax = 0.f, ay = 0.f, az = 0.f;
  if (tid < Nn){
    int n = b*Nn + tid;
    q  = Q[n]; ae = AE[n];
    px = POS[n*3+0]; py = POS[n*3+1]; pz = POS[n*3+2];
    ax = AD[3*n+0]; ay = AD[3*n+1]; az = AD[3*n+2];
    qs[tid] = q;
    ps[tid][0] = px; ps[tid][1] = py; ps[tid][2] = pz;
  }
  __syncthreads();
  float invN = 1.0f / (float)Nn;
  float cx = rsum32(px) * invN;
  float cy = rsum32(py) * invN;
  float cz = rsum32(pz) * invN;
  float dipx = rsum32(q*(px - cx) + ax);
  float dipy = rsum32(q*(py - cy) + ay);
  float dipz = rsum32(q*(pz - cz) + az);
  float sae  = rsum32(ae);

  float cl = 0.0f;
  for (int e = tid; e < Eb; e += 64){
    int dd = dst_idx[e], ss = src_idx[e];
    float dx = ps[ss][0] - ps[dd][0];
    float dy = ps[ss][1] - ps[dd][1];
    float dz = ps[ss][2] - ps[dd][2];
    float r = sqrtf(dx*dx + dy*dy + dz*dz);
    cl += qs[ss]*qs[dd] / (r + 1e-10f);
  }
  #pragma unroll
  for (int s = 32; s > 0; s >>= 1) cl += __shfl_xor(cl, s, 64);

  if (tid == 0){
    out[b] = sae + 0.5f*cl*14.399645f;
    out[Bv + b*3 + 0] = dipx;
    out[Bv + b*3 + 1] = dipy;
    out[Bv + b*3 + 2] = dipz;
  }
}

// ---------------- host launcher -----------------------------------------------
extern "C" void kernel_launch(void* const* d_in, const int* in_sizes, int n_in,
                              void* d_out, int out_size, void* d_ws, size_t ws_size,
                              hipStream_t stream) {
  (void)n_in; (void)out_size; (void)ws_size;
  const int*   Z     = (const int*)  d_in[0];
  const float* POS   = (const float*)d_in[1];
  const float* Ef    = (const float*)d_in[2];
  const int*   dst   = (const int*)  d_in[3];
  const int*   src   = (const int*)  d_in[4];
  const float* embed = (const float*)d_in[6];
  const float* Wmp   = (const float*)d_in[7];
  const float* Wd    = (const float*)d_in[8];
  const float* bd    = (const float*)d_in[9];
  const float* Wt    = (const float*)d_in[10];
  const float* Wtd1  = (const float*)d_in[11];
  const float* Wtd2  = (const float*)d_in[12];
  const float* Wtdp  = (const float*)d_in[13];
  const float* Wh    = (const float*)d_in[14];
  const float* bh    = (const float*)d_in[15];
  const float* Wq    = (const float*)d_in[16];
  const float* Wdip1 = (const float*)d_in[17];
  const float* Wdip2 = (const float*)d_in[18];
  const float* Wdipp = (const float*)d_in[19];
  const float* wdip  = (const float*)d_in[20];
  const float* We    = (const float*)d_in[21];
  const float* be    = (const float*)d_in[22];
  const float* ebias = (const float*)d_in[23];

  const int BN = in_sizes[0];        // 1024
  const int Bv = in_sizes[2] / 3;    // 32
  const int Nn = BN / Bv;            // 32
  const int Eb = in_sizes[3];        // 992

  float* wsf = (float*)d_ws;
  float* Xa  = wsf;
  float* Xb  = Xa  + (size_t)BN*576;
  float* XEF = Xb  + (size_t)BN*576;
  float* Qb  = XEF + (size_t)BN*576;
  float* AEb = Qb  + BN;
  float* AD  = AEb + BN;

  KParams p{};
  p.POS = POS; p.Z = Z; p.Ef = Ef; p.src = src; p.embed = embed;
  p.Wh = Wh; p.bh = bh; p.Wq = Wq;
  p.Wdip1 = Wdip1; p.Wdip2 = Wdip2; p.Wdipp = Wdipp; p.wdip = wdip;
  p.We = We; p.be = be; p.ebias = ebias;
  p.Q = Qb; p.AE = AEb; p.AD = AD;

  // iter 0
  p.Wmp = Wmp; p.Wd = Wd; p.bd = bd; p.Wt = Wt;
  p.Wtd1 = Wtd1; p.Wtd2 = Wtd2; p.Wtdp = Wtdp;
  p.Xc = Xa; p.Xn = Xa; p.XEF = XEF;
  k_iter<0><<<BN, 256, 0, stream>>>(p);

  // iter 1
  p.Wmp = Wmp + 768; p.Wd = Wd + 1024; p.bd = bd + 32; p.Wt = Wt + 864;
  p.Wtd1 = Wtd1 + 1024; p.Wtd2 = Wtd2 + 1024; p.Wtdp = Wtdp + 864;
  p.Xc = Xa; p.Xn = Xb;
  k_iter<1><<<BN, 256, 0, stream>>>(p);

  // iter 2 + head
  p.Wmp = Wmp + 2*768; p.Wd = Wd + 2*1024; p.bd = bd + 2*32; p.Wt = Wt + 2*864;
  p.Wtd1 = Wtd1 + 2*1024; p.Wtd2 = Wtd2 + 2*1024; p.Wtdp = Wtdp + 2*864;
  p.Xc = Xb; p.Xn = Xa;
  k_iter<2><<<BN, 256, 0, stream>>>(p);

  k_final<<<Bv, 64, 0, stream>>>(Qb, AEb, AD, POS, dst, src,
                                 (float*)d_out, Nn, Eb, Bv);
}